// Round 9
// baseline (148.622 us; speedup 1.0000x reference)
//
#include <hip/hip_runtime.h>
#include <math.h>

#define B_    32
#define CIN_  256
#define HW_   784
#define H_    28
#define W_    28
#define COUT_ 256
#define KEXP_ 4
#define HID_  64

typedef short short8 __attribute__((ext_vector_type(8)));
typedef unsigned short ushort4v __attribute__((ext_vector_type(4)));
typedef unsigned short ushort8v __attribute__((ext_vector_type(8)));
typedef float floatx16 __attribute__((ext_vector_type(16)));

#define AS1 __attribute__((address_space(1)))
#define AS3 __attribute__((address_space(3)))
__device__ __forceinline__ void glds16(const void* g, void* l) {
    __builtin_amdgcn_global_load_lds((const AS1 unsigned int*)g,
                                     (AS3 unsigned int*)l, 16, 0, 0);
}
#define VMW(N) asm volatile("s_waitcnt vmcnt(" #N ")" ::: "memory")
#define SB()   __builtin_amdgcn_sched_barrier(0)

__device__ __forceinline__ unsigned short f2bf(float f) {
    union { float f; unsigned int u; } v; v.f = f;
    unsigned int r = (v.u + 0x7FFFu + ((v.u >> 16) & 1u)) >> 16;
    return (unsigned short)r;
}

// ---------------- Kernel 1: transpose + partial pool (+ zero-page init) ----------------
__global__ __launch_bounds__(256) void xpose_pool_kernel(const float* __restrict__ x,
                                                         unsigned short* __restrict__ x_t,
                                                         float* __restrict__ partial,
                                                         float* __restrict__ zp) {
    __shared__ float tile[32][33];
    int bid = blockIdx.x;              // 32 * 8 * 25
    int b   = bid / 200;
    int rem = bid - b * 200;
    int icg = rem / 25;
    int pxt = rem % 25;
    int ic0 = icg * 32;
    int px0 = pxt * 32;
    int t = threadIdx.x;
    if (bid == 0 && t == 0) {
        float4 z; z.x = 0.f; z.y = 0.f; z.z = 0.f; z.w = 0.f;
        *(float4*)zp = z;
    }
    int c = t & 31, rr = t >> 5;
    #pragma unroll
    for (int r = 0; r < 4; ++r) {
        int icr = rr + r * 8;
        int px = px0 + c;
        float v = (px < HW_) ? x[((size_t)(b * CIN_ + ic0 + icr)) * HW_ + px] : 0.f;
        tile[icr][c] = v;
    }
    __syncthreads();
    #pragma unroll
    for (int r = 0; r < 4; ++r) {
        int pxr = rr + r * 8;
        int px = px0 + pxr;
        if (px < HW_)
            x_t[((size_t)b * HW_ + px) * CIN_ + ic0 + c] = f2bf(tile[c][pxr]);
    }
    if (t < 32) {
        float s = 0.f;
        #pragma unroll
        for (int cc = 0; cc < 32; ++cc) s += tile[t][cc];
        partial[((size_t)b * 25 + pxt) * CIN_ + ic0 + t] = s * (1.0f / HW_);
    }
}

// ---------------- standalone pool (fallback path only) ----------------
__global__ __launch_bounds__(256) void pool_kernel(const float* __restrict__ x,
                                                   float* __restrict__ pooled) {
    int w = blockIdx.x * 4 + (threadIdx.x >> 6);
    int lane = threadIdx.x & 63;
    const float* p = x + (size_t)w * HW_;
    float s = 0.f;
    for (int i = lane; i < HW_; i += 64) s += p[i];
    for (int off = 32; off; off >>= 1) s += __shfl_down(s, off);
    if (lane == 0) pooled[w] = s * (1.0f / HW_);
}

// ---------------- Kernel 2: SE MLP + softmax ----------------
__global__ __launch_bounds__(256) void se3_kernel(const float* __restrict__ partial,
                                                  const float* __restrict__ fc1_w,
                                                  const float* __restrict__ fc2_w,
                                                  const float* __restrict__ fc2_b,
                                                  float* __restrict__ prob) {
    __shared__ float pl[CIN_];
    __shared__ float h[HID_];
    __shared__ float wb[16640];
    int b = blockIdx.x, t = threadIdx.x;
    {
        float s = 0.f;
        for (int pt = 0; pt < 25; ++pt)
            s += partial[((size_t)b * 25 + pt) * CIN_ + t];
        pl[t] = s;
    }
    #pragma unroll
    for (int i = 0; i < 16; ++i) {
        int l = t + i * 256;
        float4 v = *(const float4*)(fc1_w + (size_t)l * 4);
        int r = l >> 6, cc = (l & 63) * 4;
        float* dst = &wb[r * 257 + cc];
        dst[0] = v.x; dst[1] = v.y; dst[2] = v.z; dst[3] = v.w;
    }
    __syncthreads();
    if (t < HID_) {
        float s = 0.f;
        const float* wr = &wb[t * 257];
        for (int c = 0; c < CIN_; ++c) s += pl[c] * wr[c];
        h[t] = fmaxf(s, 0.f);
    }
    float yk[KEXP_];
    for (int k = 0; k < KEXP_; ++k) {
        __syncthreads();
        #pragma unroll
        for (int i = 0; i < 16; ++i) {
            int l = t + i * 256;
            float4 v = *(const float4*)(fc2_w + (size_t)k * COUT_ * HID_ + (size_t)l * 4);
            int o = l >> 4, jj = (l & 15) * 4;
            float* dst = &wb[o * 65 + jj];
            dst[0] = v.x; dst[1] = v.y; dst[2] = v.z; dst[3] = v.w;
        }
        __syncthreads();
        float s = fc2_b[k * COUT_ + t];
        const float* wr = &wb[t * 65];
        #pragma unroll
        for (int j = 0; j < HID_; ++j) s += h[j] * wr[j];
        yk[k] = s * 0.125f;
    }
    float m = yk[0];
    for (int k = 1; k < KEXP_; ++k) m = fmaxf(m, yk[k]);
    float e[KEXP_], sum = 0.f;
    for (int k = 0; k < KEXP_; ++k) { e[k] = expf(yk[k] - m); sum += e[k]; }
    float inv = 1.0f / sum;
    for (int k = 0; k < KEXP_; ++k)
        prob[b * (KEXP_ * COUT_) + k * COUT_ + t] = e[k] * inv;
}

// ---------------- SE from pooled (fallback path only) ----------------
__global__ __launch_bounds__(256) void se2_kernel(const float* __restrict__ pooled,
                                                  const float* __restrict__ fc1_w,
                                                  const float* __restrict__ fc2_w,
                                                  const float* __restrict__ fc2_b,
                                                  float* __restrict__ prob) {
    __shared__ float pl[CIN_];
    __shared__ float h[HID_];
    __shared__ float wb[16640];
    int b = blockIdx.x, t = threadIdx.x;
    pl[t] = pooled[b * CIN_ + t];
    #pragma unroll
    for (int i = 0; i < 16; ++i) {
        int l = t + i * 256;
        float4 v = *(const float4*)(fc1_w + (size_t)l * 4);
        int r = l >> 6, cc = (l & 63) * 4;
        float* dst = &wb[r * 257 + cc];
        dst[0] = v.x; dst[1] = v.y; dst[2] = v.z; dst[3] = v.w;
    }
    __syncthreads();
    if (t < HID_) {
        float s = 0.f;
        const float* wr = &wb[t * 257];
        for (int c = 0; c < CIN_; ++c) s += pl[c] * wr[c];
        h[t] = fmaxf(s, 0.f);
    }
    float yk[KEXP_];
    for (int k = 0; k < KEXP_; ++k) {
        __syncthreads();
        #pragma unroll
        for (int i = 0; i < 16; ++i) {
            int l = t + i * 256;
            float4 v = *(const float4*)(fc2_w + (size_t)k * COUT_ * HID_ + (size_t)l * 4);
            int o = l >> 4, jj = (l & 15) * 4;
            float* dst = &wb[o * 65 + jj];
            dst[0] = v.x; dst[1] = v.y; dst[2] = v.z; dst[3] = v.w;
        }
        __syncthreads();
        float s = fc2_b[k * COUT_ + t];
        const float* wr = &wb[t * 65];
        #pragma unroll
        for (int j = 0; j < HID_; ++j) s += h[j] * wr[j];
        yk[k] = s * 0.125f;
    }
    float m = yk[0];
    for (int k = 1; k < KEXP_; ++k) m = fmaxf(m, yk[k]);
    float e[KEXP_], sum = 0.f;
    for (int k = 0; k < KEXP_; ++k) { e[k] = expf(yk[k] - m); sum += e[k]; }
    float inv = 1.0f / sum;
    for (int k = 0; k < KEXP_; ++k)
        prob[b * (KEXP_ * COUT_) + k * COUT_ + t] = e[k] * inv;
}

// ---------------- Kernel 3: aggregate expert weights -> MFMA-fragment layout ----------------
__global__ __launch_bounds__(256) void agg4_kernel(const float* __restrict__ weight,
                                                   const float* __restrict__ prob,
                                                   unsigned short* __restrict__ agg) {
    __shared__ float wlds[4][32][145];
    int gid = blockIdx.x;
    int og  = gid & 7;
    int icc = (gid >> 3) & 3;
    int kk  = (gid >> 5) & 3;
    int bh  = gid >> 7;
    int oc0 = og * 32;
    int ic0 = icc * 64 + kk * 16;
    int t = threadIdx.x;

    #pragma unroll
    for (int i = 0; i < 18; ++i) {
        int idx = t + i * 256;
        int k  = idx / 1152;
        int r  = idx - k * 1152;
        int oc = r / 36;
        int f4 = r - oc * 36;
        float4 v = *(const float4*)(weight + ((size_t)(k * COUT_ + oc0 + oc) * CIN_ + ic0) * 9 + f4 * 4);
        float* dst = &wlds[k][oc][f4 * 4];
        dst[0] = v.x; dst[1] = v.y; dst[2] = v.z; dst[3] = v.w;
    }

    int lane = t & 63, wv = t >> 6;
    int ml = lane & 31, kh = lane >> 5;

    float pbr[4][4];
    #pragma unroll
    for (int bi = 0; bi < 4; ++bi) {
        int b = bh * 16 + wv * 4 + bi;
        #pragma unroll
        for (int k = 0; k < 4; ++k)
            pbr[bi][k] = prob[(size_t)b * (KEXP_ * COUT_) + k * COUT_ + oc0 + ml];
    }
    __syncthreads();

    for (int rs = 0; rs < 9; ++rs) {
        float wreg[4][8];
        #pragma unroll
        for (int k = 0; k < 4; ++k)
            #pragma unroll
            for (int j = 0; j < 8; ++j)
                wreg[k][j] = wlds[k][ml][(kh * 8 + j) * 9 + rs];
        #pragma unroll
        for (int bi = 0; bi < 4; ++bi) {
            int b = bh * 16 + wv * 4 + bi;
            ushort8v pack;
            #pragma unroll
            for (int j = 0; j < 8; ++j) {
                float s = pbr[bi][0] * wreg[0][j] + pbr[bi][1] * wreg[1][j]
                        + pbr[bi][2] * wreg[2][j] + pbr[bi][3] * wreg[3][j];
                pack[j] = f2bf(s);
            }
            *(ushort8v*)(agg + (size_t)(b * 16 + icc * 4 + kk) * 36864
                             + (size_t)rs * 4096 + og * 512 + lane * 8) = pack;
        }
    }
}

// ---------------- Kernel 4: MFMA conv, 7-row strips, DMA + counted vmcnt, pair-swizzled B ----------------
// grid = 256: b = gid&31, half = (gid>>5)&1, rowblk = gid>>6 (0..3, 7 rows each). 2 blocks/CU.
// 8 chunks of 32 ic; 6 steps/chunk (kk{0,1} x dx{0,1,2}); 48 global steps.
// Xs granule mapping (16B granules, 128B pairs): granule for (a, g) at
//   pair=a>>1, q = ((a&1)<<2 | g) ^ (pair&7); byte = pair*128 + q*16
// -> DMA-linear writes, uniform 4-lanes-per-quad reads (LDS minimum, conflict-free).
// A: per-wave 3-slot LDS ring; DMA 2 steps ahead, ds_read 1 step ahead.
// Ledger/wave (A=3 ops, Xs=5 ops): steady VMW(3); s==3/4 of staging chunks VMW(8);
// s==5 VMW(3) retires Xs before barrier; drain VMW(0) at g=46.
__global__ __launch_bounds__(256, 2) void conv_mfma9_kernel(const unsigned short* __restrict__ x_t,
                                                            const unsigned short* __restrict__ agg,
                                                            const float* __restrict__ zp,
                                                            float* __restrict__ out) {
    __shared__ __align__(16) short Xs[2][10080];   // 2 x 20160 B (1260 granules each)
    __shared__ __align__(16) short Alds[18432];    // 36864 B: 4 waves x 3 slots x 3 taps x 1KB

    int gid = blockIdx.x;
    int b      = gid & 31;
    int half   = (gid >> 5) & 1;
    int oc0    = half * 128;
    int rowblk = gid >> 6;
    int py0 = rowblk * 7;

    int t = threadIdx.x;
    int lane = t & 63, w = t >> 6;
    int ml = lane & 31, kh = lane >> 5;
    int og = half * 4 + w;

    floatx16 acc[7];
    #pragma unroll
    for (int j = 0; j < 7; ++j)
        #pragma unroll
        for (int r = 0; r < 16; ++r) acc[j][r] = 0.f;

    const unsigned short* xtb = x_t + (size_t)b * HW_ * CIN_;
    const unsigned short* ag  = agg + (size_t)b * 589824 + og * 512 + lane * 8;

    // per-lane B byte-offsets for kk=0; step applies ^ (kk<<5)
    int off0[3][9];
    #pragma unroll
    for (int dx = 0; dx < 3; ++dx)
        #pragma unroll
        for (int r = 0; r < 9; ++r) {
            int a = ml + dx + 35 * r;
            int p = a >> 1;
            int q0 = (((a & 1) << 2) | kh) ^ (p & 7);
            off0[dx][r] = p * 128 + q0 * 16;
        }

    // stage one 32-ic chunk (1260 granules) into Xs[bb]; 5 DMA ops per wave
    auto stageXs = [&](int cc, int bb) {
        #pragma unroll
        for (int i = 0; i < 5; ++i) {
            int l = t + i * 256;           // granule index
            bool act = (l < 1260);
            int pair = l >> 3, q = l & 7;
            int v = q ^ (pair & 7);
            int g8 = v & 3;
            int a  = pair * 2 + (v >> 2);
            int row = a / 35, col = a - row * 35;
            int gy = py0 - 1 + row, gx = col - 1;
            const void* src = (act && (unsigned)gy < 28u && (unsigned)gx < 28u)
                ? (const void*)(xtb + ((size_t)(gy * W_ + gx)) * CIN_ + cc * 32 + g8 * 8)
                : (const void*)zp;
            if (act)
                glds16(src, &Xs[bb][(w * 64 + i * 256) * 8]);
        }
    };

    // DMA 3 A-tap fragments (chunk cc, kk2, dx2) into ring slot
    auto dmaA = [&](int cc, int kk2, int dx2, int slot) {
        const unsigned short* sp = ag + (cc >> 1) * 147456
                                      + ((cc & 1) * 2 + kk2) * 36864 + dx2 * 4096;
        short* d = &Alds[(w * 9 + slot * 3) * 512];
        glds16(sp,         d);
        glds16(sp + 12288, d + 512);
        glds16(sp + 24576, d + 1024);
    };

    // ---- prologue: Xs chunk0, A(0), A(1); wait Xs+A0 (A1 in flight); barrier; read A0 ----
    stageXs(0, 0);     SB();
    dmaA(0, 0, 0, 0);  SB();
    dmaA(0, 0, 1, 1);  SB();
    VMW(3);            SB();
    __builtin_amdgcn_s_barrier();

    short8 Areg[2][3];
    #pragma unroll
    for (int tap = 0; tap < 3; ++tap)
        Areg[0][tap] = *(const short8*)&Alds[(w * 9 + tap) * 512 + lane * 8];

    // ---- steady chunks 0..6 ----
    for (int c = 0; c < 7; ++c) {
        const char* xb = (const char*)&Xs[0][0] + (c & 1) * 20160;
        #pragma unroll
        for (int s = 0; s < 6; ++s) {
            if (s <= 3)      { dmaA(c,     (s + 2) / 3, (s + 2) % 3, (s + 2) % 3); SB(); }
            else if (s == 4) { dmaA(c + 1, 0, 0, 0); SB(); }
            else             { dmaA(c + 1, 0, 1, 1); SB(); }
            if (s == 3) { stageXs(c + 1, (c + 1) & 1); SB(); }
            if (s == 3 || s == 4) { VMW(8); } else { VMW(3); }
            SB();
            #pragma unroll
            for (int tap = 0; tap < 3; ++tap)
                Areg[(s + 1) & 1][tap] =
                    *(const short8*)&Alds[(w * 9 + ((s + 1) % 3) * 3 + tap) * 512 + lane * 8];
            const int kx = (s / 3) << 5;
            const int dx = s % 3;
            #pragma unroll
            for (int r = 0; r < 9; ++r) {
                short8 Bf = *(const short8*)(xb + (off0[dx][r] ^ kx));
                if (r <= 6)
                    acc[r]     = __builtin_amdgcn_mfma_f32_32x32x16_bf16(Areg[s & 1][0], Bf, acc[r], 0, 0, 0);
                if (r >= 1 && r <= 7)
                    acc[r - 1] = __builtin_amdgcn_mfma_f32_32x32x16_bf16(Areg[s & 1][1], Bf, acc[r - 1], 0, 0, 0);
                if (r >= 2)
                    acc[r - 2] = __builtin_amdgcn_mfma_f32_32x32x16_bf16(Areg[s & 1][2], Bf, acc[r - 2], 0, 0, 0);
            }
            if (s == 5) __builtin_amdgcn_s_barrier();
        }
    }

    // ---- peeled chunk 7 (g = 42..47): no staging, drain ring ----
    {
        const char* xb = (const char*)&Xs[0][0] + 20160;   // buf 1
        #pragma unroll
        for (int s = 0; s < 6; ++s) {
            if (s <= 3) { dmaA(7, (s + 2) / 3, (s + 2) % 3, (s + 2) % 3); SB(); }
            if (s <= 3)      { VMW(3); }
            else if (s == 4) { VMW(0); }
            SB();
            if (s < 5) {
                #pragma unroll
                for (int tap = 0; tap < 3; ++tap)
                    Areg[(s + 1) & 1][tap] =
                        *(const short8*)&Alds[(w * 9 + ((s + 1) % 3) * 3 + tap) * 512 + lane * 8];
            }
            const int kx = (s / 3) << 5;
            const int dx = s % 3;
            #pragma unroll
            for (int r = 0; r < 9; ++r) {
                short8 Bf = *(const short8*)(xb + (off0[dx][r] ^ kx));
                if (r <= 6)
                    acc[r]     = __builtin_amdgcn_mfma_f32_32x32x16_bf16(Areg[s & 1][0], Bf, acc[r], 0, 0, 0);
                if (r >= 1 && r <= 7)
                    acc[r - 1] = __builtin_amdgcn_mfma_f32_32x32x16_bf16(Areg[s & 1][1], Bf, acc[r - 1], 0, 0, 0);
                if (r >= 2)
                    acc[r - 2] = __builtin_amdgcn_mfma_f32_32x32x16_bf16(Areg[s & 1][2], Bf, acc[r - 2], 0, 0, 0);
            }
        }
    }

    // ---- epilogue: D layout col=lane&31, row=(reg&3)+8*(reg>>2)+4*(lane>>5) ----
    if (ml < W_) {
        #pragma unroll
        for (int j = 0; j < 7; ++j) {
            float* op = out + ((size_t)(b * COUT_ + oc0 + w * 32)) * HW_ + (py0 + j) * W_ + ml;
            #pragma unroll
            for (int r = 0; r < 16; ++r) {
                int ocd = (r & 3) + 8 * (r >> 2) + 4 * kh;
                op[(size_t)ocd * HW_] = acc[j][r];
            }
        }
    }
}

// ---------------- Fallback fp32 direct conv ----------------
__global__ __launch_bounds__(256) void conv_kernel(const float* __restrict__ x,
                                                   const float* __restrict__ weight,
                                                   const float* __restrict__ prob,
                                                   float* __restrict__ out) {
    __shared__ float xs[30 * 30];
    __shared__ float wagg[8][32][12];
    __shared__ float pl[KEXP_][8];

    int b  = blockIdx.x >> 5;
    int o0 = (blockIdx.x & 31) * 8;
    int t  = threadIdx.x;

    if (t < 32) {
        int k = t >> 3, oc = t & 7;
        pl[k][oc] = prob[b * (KEXP_ * COUT_) + k * COUT_ + o0 + oc];
    }
    int p0 = t;
    int pr[4], pc[4];
    bool pv[4];
    #pragma unroll
    for (int j = 0; j < 4; ++j) {
        int p = p0 + j * 256;
        pv[j] = p < HW_;
        pr[j] = p / W_;
        pc[j] = p % W_;
    }
    float acc[8][4];
    #pragma unroll
    for (int oc = 0; oc < 8; ++oc)
        #pragma unroll
        for (int j = 0; j < 4; ++j) acc[oc][j] = 0.f;

    int aoc = t >> 5, aii = t & 31;

    for (int ic0 = 0; ic0 < CIN_; ic0 += 32) {
        __syncthreads();
        {
            float w9[9];
            #pragma unroll
            for (int j = 0; j < 9; ++j) w9[j] = 0.f;
            int i = ic0 + aii;
            #pragma unroll
            for (int k = 0; k < KEXP_; ++k) {
                float pk = pl[k][aoc];
                const float* wp = weight + ((size_t)(k * COUT_ + o0 + aoc) * CIN_ + i) * 9;
                #pragma unroll
                for (int j = 0; j < 9; ++j) w9[j] += pk * wp[j];
            }
            #pragma unroll
            for (int j = 0; j < 9; ++j) wagg[aoc][aii][j] = w9[j];
        }
        for (int ii = 0; ii < 32; ++ii) {
            int i = ic0 + ii;
            __syncthreads();
            const float* xp = x + (size_t)(b * CIN_ + i) * HW_;
            for (int e = t; e < 900; e += 256) {
                int ry = e / 30, cx = e - ry * 30;
                int gy = ry - 1, gx = cx - 1;
                float v = 0.f;
                if ((unsigned)gy < 28u && (unsigned)gx < 28u) v = xp[gy * W_ + gx];
                xs[e] = v;
            }
            __syncthreads();
            float xv[4][9];
            #pragma unroll
            for (int j = 0; j < 4; ++j) {
                if (pv[j]) {
                    const float* xr = &xs[pr[j] * 30 + pc[j]];
                    xv[j][0] = xr[0];  xv[j][1] = xr[1];  xv[j][2] = xr[2];
                    xv[j][3] = xr[30]; xv[j][4] = xr[31]; xv[j][5] = xr[32];
                    xv[j][6] = xr[60]; xv[j][7] = xr[61]; xv[j][8] = xr[62];
                } else {
                    #pragma unroll
                    for (int q = 0; q < 9; ++q) xv[j][q] = 0.f;
                }
            }
            #pragma unroll
            for (int oc = 0; oc < 8; ++oc) {
                float4 wa = *(const float4*)&wagg[oc][ii][0];
                float4 wb2 = *(const float4*)&wagg[oc][ii][4];
                float  wc = wagg[oc][ii][8];
                #pragma unroll
                for (int j = 0; j < 4; ++j) {
                    acc[oc][j] += xv[j][0] * wa.x + xv[j][1] * wa.y + xv[j][2] * wa.z
                                + xv[j][3] * wa.w + xv[j][4] * wb2.x + xv[j][5] * wb2.y
                                + xv[j][6] * wb2.z + xv[j][7] * wb2.w + xv[j][8] * wc;
                }
            }
        }
    }
    #pragma unroll
    for (int oc = 0; oc < 8; ++oc) {
        float* op = out + (size_t)(b * COUT_ + o0 + oc) * HW_ + p0;
        #pragma unroll
        for (int j = 0; j < 4; ++j)
            if (pv[j]) op[j * 256] = acc[oc][j];
    }
}

extern "C" void kernel_launch(void* const* d_in, const int* in_sizes, int n_in,
                              void* d_out, int out_size, void* d_ws, size_t ws_size,
                              hipStream_t stream) {
    const float* x     = (const float*)d_in[0];
    const float* fc1_w = (const float*)d_in[1];
    const float* fc2_w = (const float*)d_in[2];
    const float* fc2_b = (const float*)d_in[3];
    const float* weight= (const float*)d_in[4];
    float* out = (float*)d_out;

    char* ws = (char*)d_ws;
    // layout (main path): prob @0 (128KB), x_t @131072 (12.85MB), agg @12976128 (37.75MB),
    // zp @50724864 (16B zeros, after agg); partial overlaps agg start (consumed before agg4)
    float* prob = (float*)(ws);
    unsigned short* x_t = (unsigned short*)(ws + 131072);
    unsigned short* agg = (unsigned short*)(ws + 12976128);
    float* partial = (float*)(ws + 12976128);
    float* zp   = (float*)(ws + 50724864);
    const size_t WS_NEED = 50724864 + 4096;

    if (ws_size >= WS_NEED) {
        xpose_pool_kernel<<<B_ * 8 * 25, 256, 0, stream>>>(x, x_t, partial, zp);
        se3_kernel<<<B_, 256, 0, stream>>>(partial, fc1_w, fc2_w, fc2_b, prob);
        agg4_kernel<<<256, 256, 0, stream>>>(weight, prob, agg);
        conv_mfma9_kernel<<<256, 256, 0, stream>>>(x_t, agg, zp, out);
    } else {
        float* pooled = (float*)(ws + 131072);
        pool_kernel<<<(B_ * CIN_) / 4, 256, 0, stream>>>(x, pooled);
        se2_kernel<<<B_, 256, 0, stream>>>(pooled, fc1_w, fc2_w, fc2_b, prob);
        conv_kernel<<<B_ * (COUT_ / 8), 256, 0, stream>>>(x, weight, prob, out);
    }
}

// Round 10
// 143.766 us; speedup vs baseline: 1.0338x; 1.0338x over previous
//
#include <hip/hip_runtime.h>
#include <math.h>

#define B_    32
#define CIN_  256
#define HW_   784
#define H_    28
#define W_    28
#define COUT_ 256
#define KEXP_ 4
#define HID_  64

typedef short short8 __attribute__((ext_vector_type(8)));
typedef unsigned short ushort4v __attribute__((ext_vector_type(4)));
typedef unsigned short ushort8v __attribute__((ext_vector_type(8)));
typedef float floatx16 __attribute__((ext_vector_type(16)));

#define SB() __builtin_amdgcn_sched_barrier(0)

__device__ __forceinline__ unsigned short f2bf(float f) {
    union { float f; unsigned int u; } v; v.f = f;
    unsigned int r = (v.u + 0x7FFFu + ((v.u >> 16) & 1u)) >> 16;
    return (unsigned short)r;
}

// ---------------- Kernel 1: transpose + partial pool (no atomics) ----------------
__global__ __launch_bounds__(256) void xpose_pool_kernel(const float* __restrict__ x,
                                                         unsigned short* __restrict__ x_t,
                                                         float* __restrict__ partial) {
    __shared__ float tile[32][33];
    int bid = blockIdx.x;              // 32 * 8 * 25
    int b   = bid / 200;
    int rem = bid - b * 200;
    int icg = rem / 25;
    int pxt = rem % 25;
    int ic0 = icg * 32;
    int px0 = pxt * 32;
    int t = threadIdx.x;
    int c = t & 31, rr = t >> 5;
    #pragma unroll
    for (int r = 0; r < 4; ++r) {
        int icr = rr + r * 8;
        int px = px0 + c;
        float v = (px < HW_) ? x[((size_t)(b * CIN_ + ic0 + icr)) * HW_ + px] : 0.f;
        tile[icr][c] = v;
    }
    __syncthreads();
    #pragma unroll
    for (int r = 0; r < 4; ++r) {
        int pxr = rr + r * 8;
        int px = px0 + pxr;
        if (px < HW_)
            x_t[((size_t)b * HW_ + px) * CIN_ + ic0 + c] = f2bf(tile[c][pxr]);
    }
    if (t < 32) {
        float s = 0.f;
        #pragma unroll
        for (int cc = 0; cc < 32; ++cc) s += tile[t][cc];
        partial[((size_t)b * 25 + pxt) * CIN_ + ic0 + t] = s * (1.0f / HW_);
    }
}

// ---------------- standalone pool (fallback path only) ----------------
__global__ __launch_bounds__(256) void pool_kernel(const float* __restrict__ x,
                                                   float* __restrict__ pooled) {
    int w = blockIdx.x * 4 + (threadIdx.x >> 6);
    int lane = threadIdx.x & 63;
    const float* p = x + (size_t)w * HW_;
    float s = 0.f;
    for (int i = lane; i < HW_; i += 64) s += p[i];
    for (int off = 32; off; off >>= 1) s += __shfl_down(s, off);
    if (lane == 0) pooled[w] = s * (1.0f / HW_);
}

// ---------------- Kernel 2: SE MLP + softmax ----------------
__global__ __launch_bounds__(256) void se3_kernel(const float* __restrict__ partial,
                                                  const float* __restrict__ fc1_w,
                                                  const float* __restrict__ fc2_w,
                                                  const float* __restrict__ fc2_b,
                                                  float* __restrict__ prob) {
    __shared__ float pl[CIN_];
    __shared__ float h[HID_];
    __shared__ float wb[16640];
    int b = blockIdx.x, t = threadIdx.x;
    {
        float s = 0.f;
        for (int pt = 0; pt < 25; ++pt)
            s += partial[((size_t)b * 25 + pt) * CIN_ + t];
        pl[t] = s;
    }
    #pragma unroll
    for (int i = 0; i < 16; ++i) {
        int l = t + i * 256;
        float4 v = *(const float4*)(fc1_w + (size_t)l * 4);
        int r = l >> 6, cc = (l & 63) * 4;
        float* dst = &wb[r * 257 + cc];
        dst[0] = v.x; dst[1] = v.y; dst[2] = v.z; dst[3] = v.w;
    }
    __syncthreads();
    if (t < HID_) {
        float s = 0.f;
        const float* wr = &wb[t * 257];
        for (int c = 0; c < CIN_; ++c) s += pl[c] * wr[c];
        h[t] = fmaxf(s, 0.f);
    }
    float yk[KEXP_];
    for (int k = 0; k < KEXP_; ++k) {
        __syncthreads();
        #pragma unroll
        for (int i = 0; i < 16; ++i) {
            int l = t + i * 256;
            float4 v = *(const float4*)(fc2_w + (size_t)k * COUT_ * HID_ + (size_t)l * 4);
            int o = l >> 4, jj = (l & 15) * 4;
            float* dst = &wb[o * 65 + jj];
            dst[0] = v.x; dst[1] = v.y; dst[2] = v.z; dst[3] = v.w;
        }
        __syncthreads();
        float s = fc2_b[k * COUT_ + t];
        const float* wr = &wb[t * 65];
        #pragma unroll
        for (int j = 0; j < HID_; ++j) s += h[j] * wr[j];
        yk[k] = s * 0.125f;
    }
    float m = yk[0];
    for (int k = 1; k < KEXP_; ++k) m = fmaxf(m, yk[k]);
    float e[KEXP_], sum = 0.f;
    for (int k = 0; k < KEXP_; ++k) { e[k] = expf(yk[k] - m); sum += e[k]; }
    float inv = 1.0f / sum;
    for (int k = 0; k < KEXP_; ++k)
        prob[b * (KEXP_ * COUT_) + k * COUT_ + t] = e[k] * inv;
}

// ---------------- SE from pooled (fallback path only) ----------------
__global__ __launch_bounds__(256) void se2_kernel(const float* __restrict__ pooled,
                                                  const float* __restrict__ fc1_w,
                                                  const float* __restrict__ fc2_w,
                                                  const float* __restrict__ fc2_b,
                                                  float* __restrict__ prob) {
    __shared__ float pl[CIN_];
    __shared__ float h[HID_];
    __shared__ float wb[16640];
    int b = blockIdx.x, t = threadIdx.x;
    pl[t] = pooled[b * CIN_ + t];
    #pragma unroll
    for (int i = 0; i < 16; ++i) {
        int l = t + i * 256;
        float4 v = *(const float4*)(fc1_w + (size_t)l * 4);
        int r = l >> 6, cc = (l & 63) * 4;
        float* dst = &wb[r * 257 + cc];
        dst[0] = v.x; dst[1] = v.y; dst[2] = v.z; dst[3] = v.w;
    }
    __syncthreads();
    if (t < HID_) {
        float s = 0.f;
        const float* wr = &wb[t * 257];
        for (int c = 0; c < CIN_; ++c) s += pl[c] * wr[c];
        h[t] = fmaxf(s, 0.f);
    }
    float yk[KEXP_];
    for (int k = 0; k < KEXP_; ++k) {
        __syncthreads();
        #pragma unroll
        for (int i = 0; i < 16; ++i) {
            int l = t + i * 256;
            float4 v = *(const float4*)(fc2_w + (size_t)k * COUT_ * HID_ + (size_t)l * 4);
            int o = l >> 4, jj = (l & 15) * 4;
            float* dst = &wb[o * 65 + jj];
            dst[0] = v.x; dst[1] = v.y; dst[2] = v.z; dst[3] = v.w;
        }
        __syncthreads();
        float s = fc2_b[k * COUT_ + t];
        const float* wr = &wb[t * 65];
        #pragma unroll
        for (int j = 0; j < HID_; ++j) s += h[j] * wr[j];
        yk[k] = s * 0.125f;
    }
    float m = yk[0];
    for (int k = 1; k < KEXP_; ++k) m = fmaxf(m, yk[k]);
    float e[KEXP_], sum = 0.f;
    for (int k = 0; k < KEXP_; ++k) { e[k] = expf(yk[k] - m); sum += e[k]; }
    float inv = 1.0f / sum;
    for (int k = 0; k < KEXP_; ++k)
        prob[b * (KEXP_ * COUT_) + k * COUT_ + t] = e[k] * inv;
}

// ---------------- Kernel 3: aggregate expert weights -> MFMA-fragment layout ----------------
// agg element (b, oc, ic, rs) at:
//   (b*16 + icc*4 + kk)*36864 + rs*4096 + og*512 + (kh*32+ml)*8 + j      [bf16 elems]
__global__ __launch_bounds__(256) void agg4_kernel(const float* __restrict__ weight,
                                                   const float* __restrict__ prob,
                                                   unsigned short* __restrict__ agg) {
    __shared__ float wlds[4][32][145];
    int gid = blockIdx.x;
    int og  = gid & 7;
    int icc = (gid >> 3) & 3;
    int kk  = (gid >> 5) & 3;
    int bh  = gid >> 7;
    int oc0 = og * 32;
    int ic0 = icc * 64 + kk * 16;
    int t = threadIdx.x;

    #pragma unroll
    for (int i = 0; i < 18; ++i) {
        int idx = t + i * 256;
        int k  = idx / 1152;
        int r  = idx - k * 1152;
        int oc = r / 36;
        int f4 = r - oc * 36;
        float4 v = *(const float4*)(weight + ((size_t)(k * COUT_ + oc0 + oc) * CIN_ + ic0) * 9 + f4 * 4);
        float* dst = &wlds[k][oc][f4 * 4];
        dst[0] = v.x; dst[1] = v.y; dst[2] = v.z; dst[3] = v.w;
    }

    int lane = t & 63, wv = t >> 6;
    int ml = lane & 31, kh = lane >> 5;

    float pbr[4][4];
    #pragma unroll
    for (int bi = 0; bi < 4; ++bi) {
        int b = bh * 16 + wv * 4 + bi;
        #pragma unroll
        for (int k = 0; k < 4; ++k)
            pbr[bi][k] = prob[(size_t)b * (KEXP_ * COUT_) + k * COUT_ + oc0 + ml];
    }
    __syncthreads();

    for (int rs = 0; rs < 9; ++rs) {
        float wreg[4][8];
        #pragma unroll
        for (int k = 0; k < 4; ++k)
            #pragma unroll
            for (int j = 0; j < 8; ++j)
                wreg[k][j] = wlds[k][ml][(kh * 8 + j) * 9 + rs];
        #pragma unroll
        for (int bi = 0; bi < 4; ++bi) {
            int b = bh * 16 + wv * 4 + bi;
            ushort8v pack;
            #pragma unroll
            for (int j = 0; j < 8; ++j) {
                float s = pbr[bi][0] * wreg[0][j] + pbr[bi][1] * wreg[1][j]
                        + pbr[bi][2] * wreg[2][j] + pbr[bi][3] * wreg[3][j];
                pack[j] = f2bf(s);
            }
            *(ushort8v*)(agg + (size_t)(b * 16 + icc * 4 + kk) * 36864
                             + (size_t)rs * 4096 + og * 512 + lane * 8) = pack;
        }
    }
}

// ---------------- Kernel 4: MFMA conv, 2 og per wave (24 MFMA/step), pinned depth-3 A ring ----------------
// grid = 224: b = gid&31, rowblk = gid>>5 (0..6, 4 output rows each). Block covers ALL 256 oc.
// Wave w handles og = {2w, 2w+1} (64 oc). Per step: 6 B ds_reads feed 24 MFMAs.
// Global step g = c*12 + kk*3 + dx (48 steps). A-slot g&3; prefetch g+3 into (g+3)&3,
// position pinned with sched_barrier(0) so the compiler cannot sink the loads.
__global__ __launch_bounds__(256, 1) void conv_mfma10_kernel(const unsigned short* __restrict__ x_t,
                                                             const unsigned short* __restrict__ agg,
                                                             float* __restrict__ out) {
    __shared__ __align__(16) short Xs[2][6 * 35 * 72];   // 2 x 30240 B = 60480 B

    int gid = blockIdx.x;
    int b      = gid & 31;
    int rowblk = gid >> 5;
    int py0 = rowblk * 4;

    int t = threadIdx.x;
    int lane = t & 63, w = t >> 6;
    int ml = lane & 31, kh = lane >> 5;

    floatx16 acc[2][4];
    #pragma unroll
    for (int u = 0; u < 2; ++u)
        #pragma unroll
        for (int j = 0; j < 4; ++j)
            #pragma unroll
            for (int r = 0; r < 16; ++r) acc[u][j][r] = 0.f;

    const unsigned short* xtb = x_t + (size_t)b * HW_ * CIN_;
    // fragment bases for the wave's two og groups; strides (bf16 elems):
    //   icc(64ic): 147456, kk(16ic): 36864, dx: 4096, tap ky: 12288
    const unsigned short* aln0 = agg + (size_t)b * 589824 + (w * 2 + 0) * 512 + lane * 8;
    const unsigned short* aln1 = agg + (size_t)b * 589824 + (w * 2 + 1) * 512 + lane * 8;

    // ---- depth-3 A ring: slots 0..2 = steps 0..2 (icc=0, kk=0, dx=s) ----
    short8 Abuf[4][2][3];
    #pragma unroll
    for (int s = 0; s < 3; ++s) {
        #pragma unroll
        for (int tap = 0; tap < 3; ++tap) {
            Abuf[s][0][tap] = *(const short8*)(aln0 + (size_t)s * 4096 + (size_t)tap * 12288);
            Abuf[s][1][tap] = *(const short8*)(aln1 + (size_t)s * 4096 + (size_t)tap * 12288);
        }
    }
    SB();

    // ---- stage chunk 0 into buf 0 (6 rows x 35 cols x 64 ic = 1680 short8s) ----
    {
        #pragma unroll
        for (int i = 0; i < 7; ++i) {
            int l = t + i * 256;
            if (l < 1680) {
                int pos = l >> 3, g = l & 7;
                int row = pos / 35, col = pos - row * 35;
                int gy = py0 - 1 + row, gx = col - 1;
                short8 v = (short8)0;
                if ((unsigned)gy < 28u && (unsigned)gx < 28u)
                    v = *(const short8*)(xtb + ((size_t)(gy * W_ + gx)) * CIN_ + g * 8);
                *(short8*)&Xs[0][pos * 72 + g * 8] = v;
            }
        }
    }

    __syncthreads();

    #pragma unroll
    for (int c = 0; c < 4; ++c) {
        const short* xb = &Xs[c & 1][0];

        // issue staging loads for next chunk (held in regs, written after compute)
        short8 Xl[7];
        if (c < 3) {
            #pragma unroll
            for (int i = 0; i < 7; ++i) {
                int l = t + i * 256;
                short8 v = (short8)0;
                if (l < 1680) {
                    int pos = l >> 3, g = l & 7;
                    int row = pos / 35, col = pos - row * 35;
                    int gy = py0 - 1 + row, gx = col - 1;
                    if ((unsigned)gy < 28u && (unsigned)gx < 28u)
                        v = *(const short8*)(xtb + ((size_t)(gy * W_ + gx)) * CIN_ + c * 64 + 64 + g * 8);
                }
                Xl[i] = v;
            }
            SB();
        }

        #pragma unroll
        for (int s = 0; s < 12; ++s) {
            const int g  = c * 12 + s;         // global step, static
            const int gp = g + 3;              // prefetch target, static
            if (gp < 48) {
                const int cc  = gp / 12;
                const int kkp = (gp % 12) / 3;
                const int dxp = gp % 3;
                const size_t po = (size_t)cc * 147456 + (size_t)kkp * 36864 + (size_t)dxp * 4096;
                #pragma unroll
                for (int tap = 0; tap < 3; ++tap) {
                    Abuf[gp & 3][0][tap] = *(const short8*)(aln0 + po + (size_t)tap * 12288);
                    Abuf[gp & 3][1][tap] = *(const short8*)(aln1 + po + (size_t)tap * 12288);
                }
                SB();                           // pin prefetch position — do not sink
            }
            const int kk = s / 3, dx = s % 3;
            const int sl = g & 3;
            int va = (ml + dx) * 72 + kk * 16 + kh * 8;
            #pragma unroll
            for (int r = 0; r < 6; ++r) {
                short8 Bf = *(const short8*)&xb[r * 2520 + va];
                #pragma unroll
                for (int u = 0; u < 2; ++u) {
                    if (r <= 3)
                        acc[u][r]     = __builtin_amdgcn_mfma_f32_32x32x16_bf16(Abuf[sl][u][0], Bf, acc[u][r], 0, 0, 0);
                    if (r >= 1 && r <= 4)
                        acc[u][r - 1] = __builtin_amdgcn_mfma_f32_32x32x16_bf16(Abuf[sl][u][1], Bf, acc[u][r - 1], 0, 0, 0);
                    if (r >= 2)
                        acc[u][r - 2] = __builtin_amdgcn_mfma_f32_32x32x16_bf16(Abuf[sl][u][2], Bf, acc[u][r - 2], 0, 0, 0);
                }
            }
        }

        if (c < 3) {
            short* dstb = &Xs[(c & 1) ^ 1][0];
            #pragma unroll
            for (int i = 0; i < 7; ++i) {
                int l = t + i * 256;
                if (l < 1680) {
                    int pos = l >> 3, g = l & 7;
                    *(short8*)&dstb[pos * 72 + g * 8] = Xl[i];
                }
            }
        }
        __syncthreads();
    }

    // ---- epilogue: D layout col=lane&31, row=(reg&3)+8*(reg>>2)+4*(lane>>5) ----
    if (ml < W_) {
        #pragma unroll
        for (int u = 0; u < 2; ++u) {
            #pragma unroll
            for (int j = 0; j < 4; ++j) {
                float* op = out + ((size_t)(b * COUT_ + w * 64 + u * 32)) * HW_ + (py0 + j) * W_ + ml;
                #pragma unroll
                for (int r = 0; r < 16; ++r) {
                    int ocd = (r & 3) + 8 * (r >> 2) + 4 * kh;
                    op[(size_t)ocd * HW_] = acc[u][j][r];
                }
            }
        }
    }
}

// ---------------- Fallback fp32 direct conv ----------------
__global__ __launch_bounds__(256) void conv_kernel(const float* __restrict__ x,
                                                   const float* __restrict__ weight,
                                                   const float* __restrict__ prob,
                                                   float* __restrict__ out) {
    __shared__ float xs[30 * 30];
    __shared__ float wagg[8][32][12];
    __shared__ float pl[KEXP_][8];

    int b  = blockIdx.x >> 5;
    int o0 = (blockIdx.x & 31) * 8;
    int t  = threadIdx.x;

    if (t < 32) {
        int k = t >> 3, oc = t & 7;
        pl[k][oc] = prob[b * (KEXP_ * COUT_) + k * COUT_ + o0 + oc];
    }
    int p0 = t;
    int pr[4], pc[4];
    bool pv[4];
    #pragma unroll
    for (int j = 0; j < 4; ++j) {
        int p = p0 + j * 256;
        pv[j] = p < HW_;
        pr[j] = p / W_;
        pc[j] = p % W_;
    }
    float acc[8][4];
    #pragma unroll
    for (int oc = 0; oc < 8; ++oc)
        #pragma unroll
        for (int j = 0; j < 4; ++j) acc[oc][j] = 0.f;

    int aoc = t >> 5, aii = t & 31;

    for (int ic0 = 0; ic0 < CIN_; ic0 += 32) {
        __syncthreads();
        {
            float w9[9];
            #pragma unroll
            for (int j = 0; j < 9; ++j) w9[j] = 0.f;
            int i = ic0 + aii;
            #pragma unroll
            for (int k = 0; k < KEXP_; ++k) {
                float pk = pl[k][aoc];
                const float* wp = weight + ((size_t)(k * COUT_ + o0 + aoc) * CIN_ + i) * 9;
                #pragma unroll
                for (int j = 0; j < 9; ++j) w9[j] += pk * wp[j];
            }
            #pragma unroll
            for (int j = 0; j < 9; ++j) wagg[aoc][aii][j] = w9[j];
        }
        for (int ii = 0; ii < 32; ++ii) {
            int i = ic0 + ii;
            __syncthreads();
            const float* xp = x + (size_t)(b * CIN_ + i) * HW_;
            for (int e = t; e < 900; e += 256) {
                int ry = e / 30, cx = e - ry * 30;
                int gy = ry - 1, gx = cx - 1;
                float v = 0.f;
                if ((unsigned)gy < 28u && (unsigned)gx < 28u) v = xp[gy * W_ + gx];
                xs[e] = v;
            }
            __syncthreads();
            float xv[4][9];
            #pragma unroll
            for (int j = 0; j < 4; ++j) {
                if (pv[j]) {
                    const float* xr = &xs[pr[j] * 30 + pc[j]];
                    xv[j][0] = xr[0];  xv[j][1] = xr[1];  xv[j][2] = xr[2];
                    xv[j][3] = xr[30]; xv[j][4] = xr[31]; xv[j][5] = xr[32];
                    xv[j][6] = xr[60]; xv[j][7] = xr[61]; xv[j][8] = xr[62];
                } else {
                    #pragma unroll
                    for (int q = 0; q < 9; ++q) xv[j][q] = 0.f;
                }
            }
            #pragma unroll
            for (int oc = 0; oc < 8; ++oc) {
                float4 wa = *(const float4*)&wagg[oc][ii][0];
                float4 wb2 = *(const float4*)&wagg[oc][ii][4];
                float  wc = wagg[oc][ii][8];
                #pragma unroll
                for (int j = 0; j < 4; ++j) {
                    acc[oc][j] += xv[j][0] * wa.x + xv[j][1] * wa.y + xv[j][2] * wa.z
                                + xv[j][3] * wa.w + xv[j][4] * wb2.x + xv[j][5] * wb2.y
                                + xv[j][6] * wb2.z + xv[j][7] * wb2.w + xv[j][8] * wc;
                }
            }
        }
    }
    #pragma unroll
    for (int oc = 0; oc < 8; ++oc) {
        float* op = out + (size_t)(b * COUT_ + o0 + oc) * HW_ + p0;
        #pragma unroll
        for (int j = 0; j < 4; ++j)
            if (pv[j]) op[j * 256] = acc[oc][j];
    }
}

extern "C" void kernel_launch(void* const* d_in, const int* in_sizes, int n_in,
                              void* d_out, int out_size, void* d_ws, size_t ws_size,
                              hipStream_t stream) {
    const float* x     = (const float*)d_in[0];
    const float* fc1_w = (const float*)d_in[1];
    const float* fc2_w = (const float*)d_in[2];
    const float* fc2_b = (const float*)d_in[3];
    const float* weight= (const float*)d_in[4];
    float* out = (float*)d_out;

    char* ws = (char*)d_ws;
    // layout (main path): prob @0 (128KB), x_t @131072 (12.85MB), agg @12976128 (37.75MB)
    // partial pools overlap the agg region (consumed by se3 before agg4 writes)
    float* prob = (float*)(ws);
    unsigned short* x_t = (unsigned short*)(ws + 131072);
    unsigned short* agg = (unsigned short*)(ws + 12976128);
    float* partial = (float*)(ws + 12976128);
    const size_t WS_NEED = 12976128 + (size_t)B_ * 9 * COUT_ * CIN_ * 2;  // 50724864

    if (ws_size >= WS_NEED) {
        xpose_pool_kernel<<<B_ * 8 * 25, 256, 0, stream>>>(x, x_t, partial);
        se3_kernel<<<B_, 256, 0, stream>>>(partial, fc1_w, fc2_w, fc2_b, prob);
        agg4_kernel<<<256, 256, 0, stream>>>(weight, prob, agg);
        conv_mfma10_kernel<<<224, 256, 0, stream>>>(x_t, agg, out);
    } else {
        float* pooled = (float*)(ws + 131072);
        pool_kernel<<<(B_ * CIN_) / 4, 256, 0, stream>>>(x, pooled);
        se2_kernel<<<B_, 256, 0, stream>>>(pooled, fc1_w, fc2_w, fc2_b, prob);
        conv_kernel<<<B_ * (COUT_ / 8), 256, 0, stream>>>(x, weight, prob, out);
    }
}